// Round 1
// baseline (1061.893 us; speedup 1.0000x reference)
//
#include <hip/hip_runtime.h>
#include <math.h>

#define T_TOK 8192
#define A_DIM 1024
#define E_DIM 512
#define D_DIM 20
#define S_SPAN 32768
#define HID 150
#define LMAX 10

// ---------------------------------------------------------------------------
// Kernel 1: per-token attention logits  attns[t] = MLP(states[t])
// one block per token row; 192 threads (150 active for the HID dims)
// ---------------------------------------------------------------------------
__global__ void attn_kernel(const float* __restrict__ states,
                            const float* __restrict__ Wa1, const float* __restrict__ ba1,
                            const float* __restrict__ Wa2, const float* __restrict__ ba2,
                            const float* __restrict__ Wa3, const float* __restrict__ ba3,
                            float* __restrict__ attns) {
    __shared__ float row[A_DIM];
    __shared__ float h1[HID];
    __shared__ float h2[HID];
    const int t = blockIdx.x;
    const float* s = states + (size_t)t * A_DIM;
    for (int k = threadIdx.x; k < A_DIM; k += blockDim.x) row[k] = s[k];
    __syncthreads();
    const int j = threadIdx.x;
    if (j < HID) {
        float acc = ba1[j];
        #pragma unroll 8
        for (int k = 0; k < A_DIM; ++k) acc = fmaf(row[k], Wa1[k * HID + j], acc);
        h1[j] = fmaxf(acc, 0.f);
    }
    __syncthreads();
    if (j < HID) {
        float acc = ba2[j];
        #pragma unroll 5
        for (int k = 0; k < HID; ++k) acc = fmaf(h1[k], Wa2[k * HID + j], acc);
        h2[j] = fmaxf(acc, 0.f);
    }
    __syncthreads();
    if (j == 0) {
        float acc = ba3[0];
        for (int k = 0; k < HID; ++k) acc = fmaf(h2[k], Wa3[k], acc);
        attns[t] = acc;
    }
}

// ---------------------------------------------------------------------------
// Kernel 2: dense projection  out[t,:] = X[t,:] @ W   (X:[T,K], W:[K,150])
// one block per row
// ---------------------------------------------------------------------------
template <int K>
__global__ void proj_kernel(const float* __restrict__ X, const float* __restrict__ W,
                            float* __restrict__ out) {
    __shared__ float row[K];
    const int t = blockIdx.x;
    const float* x = X + (size_t)t * K;
    for (int k = threadIdx.x; k < K; k += blockDim.x) row[k] = x[k];
    __syncthreads();
    const int j = threadIdx.x;
    if (j < HID) {
        float acc = 0.f;
        #pragma unroll 8
        for (int k = 0; k < K; ++k) acc = fmaf(row[k], W[k * HID + j], acc);
        out[(size_t)t * HID + j] = acc;
    }
}

// ---------------------------------------------------------------------------
// Kernel 3: width-bucket projection  PW[b,:] = width_table[b,:] @ Ws1_w[:, :]
// 9 rows only
// ---------------------------------------------------------------------------
__global__ void width_proj_kernel(const float* __restrict__ wt, const float* __restrict__ Wpart,
                                  float* __restrict__ PW) {
    const int b = blockIdx.x;
    const int j = threadIdx.x;
    if (j < HID) {
        float acc = 0.f;
        for (int k = 0; k < D_DIM; ++k) acc = fmaf(wt[b * D_DIM + k], Wpart[k * HID + j], acc);
        PW[b * HID + j] = acc;
    }
}

// ---------------------------------------------------------------------------
// Kernel 4: per-span fused softmax-pool + 3-layer score MLP (layer1 via
// precomputed projections). one block per span.
// ---------------------------------------------------------------------------
__global__ void span_kernel(const float* __restrict__ attns,
                            const int* __restrict__ starts, const int* __restrict__ lens,
                            const float* __restrict__ Ps, const float* __restrict__ Pe,
                            const float* __restrict__ Pm, const float* __restrict__ PW,
                            const float* __restrict__ bs1,
                            const float* __restrict__ Ws2, const float* __restrict__ bs2,
                            const float* __restrict__ Ws3, const float* __restrict__ bs3,
                            float* __restrict__ out) {
    __shared__ float h1[HID];
    __shared__ float h2[HID];
    __shared__ float w[LMAX];
    __shared__ int sidx[LMAX];
    const int s = blockIdx.x;
    const int start = starts[s];
    const int len = lens[s];           // 0..9, valid positions are 0..len
    const int tid = threadIdx.x;

    if (tid == 0) {
        float a[LMAX];
        float m = -INFINITY;
        for (int l = 0; l <= len; ++l) {
            int idx = min(start + l, T_TOK - 1);
            sidx[l] = idx;
            a[l] = attns[idx];
            m = fmaxf(m, a[l]);
        }
        float sum = 0.f;
        for (int l = 0; l <= len; ++l) { a[l] = expf(a[l] - m); sum += a[l]; }
        float inv = 1.f / sum;
        for (int l = 0; l <= len; ++l) w[l] = a[l] * inv;
    }
    __syncthreads();

    const int j = tid;
    const int end = start + len;
    // width bucket: searchsorted(BINS, len+1, right) = #bins <= width
    const int width = len + 1;
    int bucket = 0;
    const int bins[8] = {1, 2, 3, 4, 8, 16, 32, 64};
    #pragma unroll
    for (int i = 0; i < 8; ++i) bucket += (bins[i] <= width) ? 1 : 0;

    if (j < HID) {
        float acc = bs1[j] + Ps[(size_t)start * HID + j] + Pe[(size_t)end * HID + j]
                  + PW[bucket * HID + j];
        for (int l = 0; l <= len; ++l)
            acc = fmaf(w[l], Pm[(size_t)sidx[l] * HID + j], acc);
        h1[j] = fmaxf(acc, 0.f);
    }
    __syncthreads();
    if (j < HID) {
        float acc = bs2[j];
        #pragma unroll 5
        for (int k = 0; k < HID; ++k) acc = fmaf(h1[k], Ws2[k * HID + j], acc);
        h2[j] = fmaxf(acc, 0.f);
    }
    __syncthreads();
    if (j == 0) {
        float acc = bs3[0];
        for (int k = 0; k < HID; ++k) acc = fmaf(h2[k], Ws3[k], acc);
        out[s] = acc;
    }
}

extern "C" void kernel_launch(void* const* d_in, const int* in_sizes, int n_in,
                              void* d_out, int out_size, void* d_ws, size_t ws_size,
                              hipStream_t stream) {
    const float* states = (const float*)d_in[0];
    const float* embeds = (const float*)d_in[1];
    const int* span_starts = (const int*)d_in[2];
    const int* span_lengths = (const int*)d_in[3];
    const float* Wa1 = (const float*)d_in[4];
    const float* ba1 = (const float*)d_in[5];
    const float* Wa2 = (const float*)d_in[6];
    const float* ba2 = (const float*)d_in[7];
    const float* Wa3 = (const float*)d_in[8];
    const float* ba3 = (const float*)d_in[9];
    const float* width_table = (const float*)d_in[10];
    const float* Ws1 = (const float*)d_in[11];
    const float* bs1 = (const float*)d_in[12];
    const float* Ws2 = (const float*)d_in[13];
    const float* bs2 = (const float*)d_in[14];
    const float* Ws3 = (const float*)d_in[15];
    const float* bs3 = (const float*)d_in[16];
    float* out = (float*)d_out;

    // workspace layout (floats)
    float* ws = (float*)d_ws;
    float* attns = ws;                          // [T]
    float* Ps = attns + T_TOK;                  // [T,150]
    float* Pe = Ps + (size_t)T_TOK * HID;       // [T,150]
    float* Pm = Pe + (size_t)T_TOK * HID;       // [T,150]
    float* PW = Pm + (size_t)T_TOK * HID;       // [9,150]

    // Ws1 row blocks: [0:1024) start, [1024:2048) end, [2048:2560) embed, [2560:2580) width
    const float* Ws1_s = Ws1;
    const float* Ws1_e = Ws1 + (size_t)A_DIM * HID;
    const float* Ws1_m = Ws1 + (size_t)2 * A_DIM * HID;
    const float* Ws1_w = Ws1 + ((size_t)2 * A_DIM + E_DIM) * HID;

    dim3 blk(192);
    attn_kernel<<<T_TOK, blk, 0, stream>>>(states, Wa1, ba1, Wa2, ba2, Wa3, ba3, attns);
    proj_kernel<A_DIM><<<T_TOK, blk, 0, stream>>>(states, Ws1_s, Ps);
    proj_kernel<A_DIM><<<T_TOK, blk, 0, stream>>>(states, Ws1_e, Pe);
    proj_kernel<E_DIM><<<T_TOK, blk, 0, stream>>>(embeds, Ws1_m, Pm);
    width_proj_kernel<<<9, blk, 0, stream>>>(width_table, Ws1_w, PW);
    span_kernel<<<S_SPAN, blk, 0, stream>>>(attns, span_starts, span_lengths,
                                            Ps, Pe, Pm, PW,
                                            bs1, Ws2, bs2, Ws3, bs3, out);
}

// Round 3
// 326.560 us; speedup vs baseline: 3.2518x; 3.2518x over previous
//
#include <hip/hip_runtime.h>
#include <math.h>

#define T_TOK 8192
#define A_DIM 1024
#define E_DIM 512
#define S_SPAN 32768
#define HID 150

typedef __attribute__((ext_vector_type(8))) short short8;
typedef __attribute__((ext_vector_type(4))) float f32x4;
typedef __attribute__((ext_vector_type(4))) unsigned int u32x4;

__device__ __forceinline__ unsigned short f2bf(float f) {
    unsigned int u = __builtin_bit_cast(unsigned int, f);
    u += 0x7FFFu + ((u >> 16) & 1u);          // RNE
    return (unsigned short)(u >> 16);
}
__device__ __forceinline__ float bf2f(unsigned short h) {
    unsigned int u = ((unsigned int)h) << 16;
    return __builtin_bit_cast(float, u);
}

struct Epi {
    float* out[3];
    const float* bias[3];
    int ldo[3];
    int relu[3];
};

// ---------------------------------------------------------------------------
// Convert/transpose weights: dst[j][k] = bf16(src[k*150 + j]), zero-padded.
// src is [K0 x 150] row-major; dst is [160 x Kpad] bf16.
// ---------------------------------------------------------------------------
__global__ void convert_wt(const float* __restrict__ src, unsigned short* __restrict__ dst,
                           int K0, int Kpad) {
    int idx = blockIdx.x * 256 + threadIdx.x;
    int total = 160 * Kpad;
    if (idx >= total) return;
    int j = idx / Kpad, k = idx - j * Kpad;
    float v = (j < HID && k < K0) ? src[(size_t)k * HID + j] : 0.f;
    dst[idx] = f2bf(v);
}

// ---------------------------------------------------------------------------
// PW[b][j] = sum_k width_table[b][k] * Ws1[(2560+k)*150 + j]   (fp32, tiny)
// ---------------------------------------------------------------------------
__global__ void width_proj_kernel(const float* __restrict__ wt, const float* __restrict__ Ws1w,
                                  float* __restrict__ PW) {
    int b = blockIdx.x, j = threadIdx.x;
    if (j < HID) {
        float acc = 0.f;
        for (int k = 0; k < 20; ++k) acc = fmaf(wt[b * 20 + k], Ws1w[k * HID + j], acc);
        PW[b * HID + j] = acc;
    }
}

// ---------------------------------------------------------------------------
// MFMA GEMM: C[M x 160*G] = A(fp32,[M x K]) @ Wt(bf16,[G*160 x K], k-contig)
// Block: 256 thr = 4 waves, each wave 32 rows (2 m-tiles), 10 n-tiles.
// A split in-register into bf16 hi/lo (2 MFMAs per frag pair); W plain bf16.
// grid = (M/128) * G, g = blockIdx.x / nrb  (keeps same rows on same XCD).
// ---------------------------------------------------------------------------
template <int K, int G>
__global__ __launch_bounds__(256) void gemm_kernel(int nrb, const float* __restrict__ A, int lda,
                                                   const unsigned short* __restrict__ Wt, Epi epi) {
    constexpr int BK = 64;
    constexpr int LDW = 88;   // ushort stride: 176 B = 16B-aligned, 2-way-bank (free)
    __shared__ unsigned short WtL[160 * LDW];

    const int g   = (G == 1) ? 0 : (blockIdx.x / nrb);
    const int rb  = (G == 1) ? blockIdx.x : (blockIdx.x % nrb);
    const int tid = threadIdx.x;
    const int wid = tid >> 6;
    const int lane = tid & 63;
    const int l15 = lane & 15;
    const int quad = lane >> 4;
    const int row_base = rb * 128 + wid * 32;
    const unsigned short* Wg = Wt + (size_t)g * 160 * K;

    f32x4 acc[2][10];
    #pragma unroll
    for (int mt = 0; mt < 2; ++mt)
        #pragma unroll
        for (int nt = 0; nt < 10; ++nt) acc[mt][nt] = (f32x4){0.f, 0.f, 0.f, 0.f};

    for (int c = 0; c < K / BK; ++c) {
        __syncthreads();
        // cooperative stage of Wt chunk [160][64] -> LDS
        // 160 rows x 64 ushorts = 160 x 8 units of 16B = 1280 units
        for (int u = tid; u < 1280; u += 256) {
            int n = u >> 3, kq = u & 7;
            *(u32x4*)&WtL[n * LDW + kq * 8] =
                *(const u32x4*)(Wg + (size_t)n * K + c * BK + kq * 8);
        }
        __syncthreads();
        #pragma unroll
        for (int ks = 0; ks < 2; ++ks) {
            const int kk = c * BK + ks * 32;
            short8 ah[2], al[2];
            #pragma unroll
            for (int mt = 0; mt < 2; ++mt) {
                const float* ap = A + (size_t)(row_base + mt * 16 + l15) * lda + kk + quad * 8;
                f32x4 f0 = *(const f32x4*)ap;
                f32x4 f1 = *(const f32x4*)(ap + 4);
                #pragma unroll
                for (int j = 0; j < 8; ++j) {
                    float fv = (j < 4) ? f0[j] : f1[j - 4];
                    unsigned short h = f2bf(fv);
                    float r = fv - bf2f(h);
                    ah[mt][j] = (short)h;
                    al[mt][j] = (short)f2bf(r);
                }
            }
            #pragma unroll
            for (int nt = 0; nt < 10; ++nt) {
                short8 bv = *(const short8*)&WtL[(nt * 16 + l15) * LDW + ks * 32 + quad * 8];
                #pragma unroll
                for (int mt = 0; mt < 2; ++mt) {
                    acc[mt][nt] = __builtin_amdgcn_mfma_f32_16x16x32_bf16(ah[mt], bv, acc[mt][nt], 0, 0, 0);
                    acc[mt][nt] = __builtin_amdgcn_mfma_f32_16x16x32_bf16(al[mt], bv, acc[mt][nt], 0, 0, 0);
                }
            }
        }
    }

    float* outp = epi.out[g];
    const float* bias = epi.bias[g];
    const int ldo = epi.ldo[g];
    const int rel = epi.relu[g];
    #pragma unroll
    for (int mt = 0; mt < 2; ++mt)
        #pragma unroll
        for (int nt = 0; nt < 10; ++nt) {
            int col = nt * 16 + l15;
            float bv_ = (bias != nullptr && col < HID) ? bias[col] : 0.f;
            #pragma unroll
            for (int r = 0; r < 4; ++r) {
                int row = row_base + mt * 16 + quad * 4 + r;
                float v = acc[mt][nt][r] + bv_;
                if (rel) v = fmaxf(v, 0.f);
                outp[(size_t)row * ldo + col] = v;
            }
        }
}

// ---------------------------------------------------------------------------
// span layer-1: one wave per span. softmax over <=10 logits via shuffles,
// h1[j] = relu(bs1 + Ps[start] + Pe[end] + PW[bucket] + sum_l w_l*Pm[idx_l])
// writes SH1 [S x 192] cols 0..149 (pad cols pre-zeroed).
// ---------------------------------------------------------------------------
__global__ __launch_bounds__(256) void span_l1_kernel(const float* __restrict__ attns,
                                                      const int* __restrict__ starts,
                                                      const int* __restrict__ lens,
                                                      const float* __restrict__ Ps,
                                                      const float* __restrict__ Pe,
                                                      const float* __restrict__ Pm,
                                                      const float* __restrict__ PW,
                                                      const float* __restrict__ bs1,
                                                      float* __restrict__ SH1) {
    const int wid = threadIdx.x >> 6, lane = threadIdx.x & 63;
    const int s = blockIdx.x * 4 + wid;
    const int start = starts[s];
    const int len = lens[s];

    const int iv = min(start + lane, T_TOK - 1);
    float a = (lane <= len) ? attns[iv] : -INFINITY;
    float m = a;
    #pragma unroll
    for (int off = 32; off; off >>= 1) m = fmaxf(m, __shfl_xor(m, off));
    float e = (lane <= len) ? __expf(a - m) : 0.f;
    float ssum = e;
    #pragma unroll
    for (int off = 32; off; off >>= 1) ssum += __shfl_xor(ssum, off);
    float wv = e / ssum;

    float wl[10]; int il[10];
    #pragma unroll
    for (int l = 0; l < 10; ++l) { wl[l] = __shfl(wv, l); il[l] = __shfl(iv, l); }

    const int end = start + len;
    const int width = len + 1;
    const int bucket = (width >= 1) + (width >= 2) + (width >= 3) + (width >= 4) +
                       (width >= 8) + (width >= 16) + (width >= 32) + (width >= 64);

    for (int j = lane; j < HID; j += 64) {
        float acc = bs1[j] + Ps[(size_t)start * 160 + j] + Pe[(size_t)end * 160 + j] +
                    PW[bucket * HID + j];
        #pragma unroll
        for (int l = 0; l < 10; ++l) acc = fmaf(wl[l], Pm[(size_t)il[l] * 160 + j], acc);
        SH1[(size_t)s * 192 + j] = fmaxf(acc, 0.f);
    }
}

// ---------------------------------------------------------------------------
// wave-per-row dot: out[s] = b3 + sum_{k<150} X[s*ldx + k] * v[k]
// ---------------------------------------------------------------------------
__global__ __launch_bounds__(256) void wavedot_kernel(const float* __restrict__ X, int ldx,
                                                      const float* __restrict__ v,
                                                      const float* __restrict__ b3,
                                                      float* __restrict__ out, int n) {
    const int wid = threadIdx.x >> 6, lane = threadIdx.x & 63;
    const int nw = gridDim.x * 4;
    const float vk0 = v[lane];
    const float vk1 = (lane + 64 < HID) ? v[lane + 64] : 0.f;
    const float vk2 = (lane + 128 < HID) ? v[lane + 128] : 0.f;
    const float bb = b3[0];
    for (int s = blockIdx.x * 4 + wid; s < n; s += nw) {
        const float* x = X + (size_t)s * ldx;
        float p = x[lane] * vk0 + x[lane + 64] * vk1 +
                  ((lane + 128 < HID) ? x[lane + 128] * vk2 : 0.f);
        #pragma unroll
        for (int off = 32; off; off >>= 1) p += __shfl_xor(p, off);
        if (lane == 0) out[s] = p + bb;
    }
}

extern "C" void kernel_launch(void* const* d_in, const int* in_sizes, int n_in,
                              void* d_out, int out_size, void* d_ws, size_t ws_size,
                              hipStream_t stream) {
    const float* states = (const float*)d_in[0];
    const float* embeds = (const float*)d_in[1];
    const int* span_starts = (const int*)d_in[2];
    const int* span_lengths = (const int*)d_in[3];
    const float* Wa1 = (const float*)d_in[4];
    const float* ba1 = (const float*)d_in[5];
    const float* Wa2 = (const float*)d_in[6];
    const float* ba2 = (const float*)d_in[7];
    const float* Wa3 = (const float*)d_in[8];
    const float* ba3 = (const float*)d_in[9];
    const float* width_table = (const float*)d_in[10];
    const float* Ws1 = (const float*)d_in[11];
    const float* bs1 = (const float*)d_in[12];
    const float* Ws2 = (const float*)d_in[13];
    const float* bs2 = (const float*)d_in[14];
    const float* Ws3 = (const float*)d_in[15];
    const float* bs3 = (const float*)d_in[16];
    float* out = (float*)d_out;

    // ---- workspace layout (byte offsets, all 256B-multiples) ----
    char* w = (char*)d_ws;
    unsigned short* WtA  = (unsigned short*)w;              w += 480 * 1024 * 2;   // 983040
    unsigned short* WtE  = (unsigned short*)w;              w += 160 * 512 * 2;    // 163840
    unsigned short* Wa2t = (unsigned short*)w;              w += 160 * 192 * 2;    // 61440
    unsigned short* Ws2t = (unsigned short*)w;              w += 160 * 192 * 2;    // 61440
    float* PW    = (float*)w;                               w += 5632;             // 9x150 f32
    float* attns = (float*)w;                               w += 8192 * 4;
    float* Ps    = (float*)w;                               w += (size_t)8192 * 160 * 4;
    float* Pe    = (float*)w;                               w += (size_t)8192 * 160 * 4;
    float* Pm    = (float*)w;                               w += (size_t)8192 * 160 * 4;
    float* SH1   = (float*)w;                               w += (size_t)32768 * 192 * 4;
    float* H1A   = SH1;   // [8192 x 192], dead before SH1 is (re)written
    float* SH2   = (float*)w;                               w += (size_t)32768 * 160 * 4;
    float* H2A   = SH2;   // [8192 x 160], dead before SH2 is written

    // zero SH1 region (also zeroes H1A pad cols 160..191)
    hipMemsetAsync(SH1, 0, (size_t)32768 * 192 * 4, stream);

    // ---- weight conversion (transpose + bf16 + pad) ----
    int nblk = (160 * 1024 + 255) / 256;
    convert_wt<<<nblk, 256, 0, stream>>>(Wa1,                 WtA,               1024, 1024);
    convert_wt<<<nblk, 256, 0, stream>>>(Ws1,                 WtA + 160 * 1024,  1024, 1024);
    convert_wt<<<nblk, 256, 0, stream>>>(Ws1 + 1024 * 150,    WtA + 320 * 1024,  1024, 1024);
    convert_wt<<<(160 * 512 + 255) / 256, 256, 0, stream>>>(Ws1 + 2048 * 150, WtE, 512, 512);
    convert_wt<<<(160 * 192 + 255) / 256, 256, 0, stream>>>(Wa2, Wa2t, 150, 192);
    convert_wt<<<(160 * 192 + 255) / 256, 256, 0, stream>>>(Ws2, Ws2t, 150, 192);
    width_proj_kernel<<<9, 160, 0, stream>>>(width_table, Ws1 + 2560 * 150, PW);

    // ---- GEMM1: states @ [Wa1 | Ws1_s | Ws1_e]  -> H1A (bias+relu), Ps, Pe ----
    Epi e1;
    e1.out[0] = H1A; e1.bias[0] = ba1;     e1.ldo[0] = 192; e1.relu[0] = 1;
    e1.out[1] = Ps;  e1.bias[1] = nullptr; e1.ldo[1] = 160; e1.relu[1] = 0;
    e1.out[2] = Pe;  e1.bias[2] = nullptr; e1.ldo[2] = 160; e1.relu[2] = 0;
    gemm_kernel<1024, 3><<<64 * 3, 256, 0, stream>>>(64, states, 1024, WtA, e1);

    // ---- GEMM2: embeds @ Ws1_m -> Pm ----
    Epi e2;
    e2.out[0] = Pm; e2.bias[0] = nullptr; e2.ldo[0] = 160; e2.relu[0] = 0;
    e2.out[1] = nullptr; e2.bias[1] = nullptr; e2.ldo[1] = 0; e2.relu[1] = 0;
    e2.out[2] = nullptr; e2.bias[2] = nullptr; e2.ldo[2] = 0; e2.relu[2] = 0;
    gemm_kernel<512, 1><<<64, 256, 0, stream>>>(64, embeds, 512, WtE, e2);

    // ---- attn layer2: H1A @ Wa2 -> H2A (bias+relu) ----
    Epi e3 = e2;
    e3.out[0] = H2A; e3.bias[0] = ba2; e3.ldo[0] = 160; e3.relu[0] = 1;
    gemm_kernel<192, 1><<<64, 256, 0, stream>>>(64, H1A, 192, Wa2t, e3);

    // ---- attn layer3: wave dot -> attns ----
    wavedot_kernel<<<64, 256, 0, stream>>>(H2A, 160, Wa3, ba3, attns, T_TOK);

    // re-zero SH1 region (H1A is dead now; restores pad cols for span GEMM)
    hipMemsetAsync(SH1, 0, (size_t)32768 * 192 * 4, stream);

    // ---- span layer1: softmax-pool + projected sums -> SH1 ----
    span_l1_kernel<<<S_SPAN / 4, 256, 0, stream>>>(attns, span_starts, span_lengths,
                                                   Ps, Pe, Pm, PW, bs1, SH1);

    // ---- span layer2: SH1 @ Ws2 -> SH2 (bias+relu) ----
    Epi e4 = e2;
    e4.out[0] = SH2; e4.bias[0] = bs2; e4.ldo[0] = 160; e4.relu[0] = 1;
    gemm_kernel<192, 1><<<256, 256, 0, stream>>>(256, SH1, 192, Ws2t, e4);

    // ---- span layer3: wave dot -> out ----
    wavedot_kernel<<<256, 256, 0, stream>>>(SH2, 160, Ws3, bs3, out, S_SPAN);
}

// Round 4
// 222.978 us; speedup vs baseline: 4.7623x; 1.4645x over previous
//
#include <hip/hip_runtime.h>
#include <math.h>

#define T_TOK 8192
#define A_DIM 1024
#define E_DIM 512
#define S_SPAN 32768
#define HID 150

typedef __attribute__((ext_vector_type(8))) short short8;
typedef __attribute__((ext_vector_type(4))) float f32x4;
typedef __attribute__((ext_vector_type(4))) unsigned int u32x4;
typedef __attribute__((ext_vector_type(4))) unsigned short u16x4;

__device__ __forceinline__ unsigned short f2bf(float f) {
    unsigned int u = __builtin_bit_cast(unsigned int, f);
    u += 0x7FFFu + ((u >> 16) & 1u);          // RNE
    return (unsigned short)(u >> 16);
}

// ---------------------------------------------------------------------------
// cast states+embeds fp32 -> bf16 (vectorized float4 -> ushort4)
// ---------------------------------------------------------------------------
#define NS4 (T_TOK * A_DIM / 4)   // 2097152
#define NE4 (T_TOK * E_DIM / 4)   // 1048576
__global__ __launch_bounds__(256) void cast_kernel(const float* __restrict__ s,
                                                   const float* __restrict__ e,
                                                   unsigned short* __restrict__ sd,
                                                   unsigned short* __restrict__ ed) {
    int idx = blockIdx.x * 256 + threadIdx.x;
    const float* src; unsigned short* dst;
    if (idx < NS4) { src = s; dst = sd; }
    else { idx -= NS4; if (idx >= NE4) return; src = e; dst = ed; }
    f32x4 v = *(const f32x4*)(src + (size_t)idx * 4);
    u16x4 o;
    o.x = f2bf(v.x); o.y = f2bf(v.y); o.z = f2bf(v.z); o.w = f2bf(v.w);
    *(u16x4*)(dst + (size_t)idx * 4) = o;
}

// ---------------------------------------------------------------------------
// weight prep: 6 transposed bf16 groups + width projection, one launch.
// each group: src [K0 x 150] row-major fp32 -> dst [160 x Kpad] bf16, 0-pad.
// ---------------------------------------------------------------------------
struct WConv { const float* src; unsigned short* dst; int K0; int Kpad; int nblk; };
struct WTab { WConv g[6]; const float* wt; const float* Ws1w; float* PW; };

__global__ __launch_bounds__(256) void wprep_kernel(WTab tab) {
    int b = blockIdx.x;
    #pragma unroll
    for (int gi = 0; gi < 6; ++gi) {
        if (b < tab.g[gi].nblk) {
            int idx = b * 256 + threadIdx.x;
            int total = 160 * tab.g[gi].Kpad;
            if (idx < total) {
                int j = idx / tab.g[gi].Kpad, k = idx - j * tab.g[gi].Kpad;
                float v = (j < HID && k < tab.g[gi].K0)
                          ? tab.g[gi].src[(size_t)k * HID + j] : 0.f;
                tab.g[gi].dst[idx] = f2bf(v);
            }
            return;
        }
        b -= tab.g[gi].nblk;
    }
    // width projection: 9 blocks
    int j = threadIdx.x;
    if (j < HID) {
        float acc = 0.f;
        for (int k = 0; k < 20; ++k)
            acc = fmaf(tab.wt[b * 20 + k], tab.Ws1w[k * HID + j], acc);
        tab.PW[b * HID + j] = acc;
    }
}

// ---------------------------------------------------------------------------
// unified MFMA GEMM: per-group C[M x 160] = A(bf16,[M x K]) @ W(bf16,[160 x K])
// block = 4 waves x 32 rows = 128 rows, 10 n-tiles, BK=64.
// epilogue modes: fp32 store / bf16 store (+bias+relu) / fused final dot.
// ---------------------------------------------------------------------------
struct GG {
    const unsigned short* A; int lda;
    const unsigned short* W; int K; int nrb;
    float* outf; unsigned short* outh; int ldo;
    const float* bias; int relu;
    const float* dotv; const float* dotb; float* dotout;
};
struct GTab { GG g[4]; int ng; };

__global__ __launch_bounds__(256) void gemm_fused(GTab tab) {
    constexpr int LDW = 88;
    __shared__ unsigned short WtL[160 * LDW];

    int b = blockIdx.x;
    int gi = 0;
    while (gi < tab.ng - 1 && b >= tab.g[gi].nrb) { b -= tab.g[gi].nrb; ++gi; }
    const GG G = tab.g[gi];

    const int tid = threadIdx.x;
    const int wid = tid >> 6;
    const int lane = tid & 63;
    const int l15 = lane & 15;
    const int quad = lane >> 4;
    const int row0 = b * 128 + wid * 32 + l15;   // mt=0 row; mt=1 row = +16
    const int K = G.K;
    const int nch = K >> 6;

    f32x4 acc[2][10];
    #pragma unroll
    for (int mt = 0; mt < 2; ++mt)
        #pragma unroll
        for (int nt = 0; nt < 10; ++nt) acc[mt][nt] = (f32x4){0.f, 0.f, 0.f, 0.f};

    for (int c = 0; c < nch; ++c) {
        __syncthreads();
        for (int u = tid; u < 1280; u += 256) {
            int n = u >> 3, kq = u & 7;
            *(u32x4*)&WtL[n * LDW + kq * 8] =
                *(const u32x4*)(G.W + (size_t)n * K + (c << 6) + kq * 8);
        }
        __syncthreads();
        #pragma unroll
        for (int ks = 0; ks < 2; ++ks) {
            const int kk = (c << 6) + ks * 32 + quad * 8;
            short8 av0 = *(const short8*)(G.A + (size_t)row0 * G.lda + kk);
            short8 av1 = *(const short8*)(G.A + (size_t)(row0 + 16) * G.lda + kk);
            #pragma unroll
            for (int nt = 0; nt < 10; ++nt) {
                short8 bv = *(const short8*)&WtL[(nt * 16 + l15) * LDW + ks * 32 + quad * 8];
                acc[0][nt] = __builtin_amdgcn_mfma_f32_16x16x32_bf16(av0, bv, acc[0][nt], 0, 0, 0);
                acc[1][nt] = __builtin_amdgcn_mfma_f32_16x16x32_bf16(av1, bv, acc[1][nt], 0, 0, 0);
            }
        }
    }

    const int rbase = b * 128 + wid * 32 + quad * 4;
    if (G.dotout) {
        // h2 = relu(acc + bias); out[row] = dot(h2, dotv) + dotb
        float part[2][4];
        #pragma unroll
        for (int mt = 0; mt < 2; ++mt)
            #pragma unroll
            for (int r = 0; r < 4; ++r) part[mt][r] = 0.f;
        #pragma unroll
        for (int nt = 0; nt < 10; ++nt) {
            int col = nt * 16 + l15;
            float bv_ = (col < HID) ? G.bias[col] : 0.f;
            float vv = (col < HID) ? G.dotv[col] : 0.f;
            #pragma unroll
            for (int mt = 0; mt < 2; ++mt)
                #pragma unroll
                for (int r = 0; r < 4; ++r)
                    part[mt][r] += fmaxf(acc[mt][nt][r] + bv_, 0.f) * vv;
        }
        #pragma unroll
        for (int mt = 0; mt < 2; ++mt)
            #pragma unroll
            for (int r = 0; r < 4; ++r) {
                float p = part[mt][r];
                #pragma unroll
                for (int off = 1; off < 16; off <<= 1) p += __shfl_xor(p, off);
                if (l15 == 0) G.dotout[rbase + mt * 16 + r] = p + G.dotb[0];
            }
    } else {
        #pragma unroll
        for (int mt = 0; mt < 2; ++mt)
            #pragma unroll
            for (int nt = 0; nt < 10; ++nt) {
                int col = nt * 16 + l15;
                float bv_ = (G.bias != nullptr && col < HID) ? G.bias[col] : 0.f;
                #pragma unroll
                for (int r = 0; r < 4; ++r) {
                    int row = rbase + mt * 16 + r;
                    float v = acc[mt][nt][r] + bv_;
                    if (G.relu) v = fmaxf(v, 0.f);
                    if (G.outh) G.outh[(size_t)row * G.ldo + col] = f2bf(v);
                    else        G.outf[(size_t)row * G.ldo + col] = v;
                }
            }
    }
}

// ---------------------------------------------------------------------------
// span layer-1: one wave per span; writes SH1 bf16 [S x 192] cols 0..149.
// ---------------------------------------------------------------------------
__global__ __launch_bounds__(256) void span_l1_kernel(const float* __restrict__ attns,
                                                      const int* __restrict__ starts,
                                                      const int* __restrict__ lens,
                                                      const float* __restrict__ Ps,
                                                      const float* __restrict__ Pe,
                                                      const float* __restrict__ Pm,
                                                      const float* __restrict__ PW,
                                                      const float* __restrict__ bs1,
                                                      unsigned short* __restrict__ SH1) {
    const int wid = threadIdx.x >> 6, lane = threadIdx.x & 63;
    const int s = blockIdx.x * 4 + wid;
    const int start = starts[s];
    const int len = lens[s];

    const int iv = min(start + lane, T_TOK - 1);
    float a = (lane <= len) ? attns[iv] : -INFINITY;
    float m = a;
    #pragma unroll
    for (int off = 32; off; off >>= 1) m = fmaxf(m, __shfl_xor(m, off));
    float e = (lane <= len) ? __expf(a - m) : 0.f;
    float ssum = e;
    #pragma unroll
    for (int off = 32; off; off >>= 1) ssum += __shfl_xor(ssum, off);
    float wv = e / ssum;

    float wl[10]; int il[10];
    #pragma unroll
    for (int l = 0; l < 10; ++l) { wl[l] = __shfl(wv, l); il[l] = __shfl(iv, l); }

    const int end = start + len;
    const int width = len + 1;
    const int bucket = (width >= 1) + (width >= 2) + (width >= 3) + (width >= 4) +
                       (width >= 8) + (width >= 16) + (width >= 32) + (width >= 64);

    for (int j = lane; j < HID; j += 64) {
        float acc = bs1[j] + Ps[(size_t)start * 160 + j] + Pe[(size_t)end * 160 + j] +
                    PW[bucket * HID + j];
        #pragma unroll
        for (int l = 0; l < 10; ++l) acc = fmaf(wl[l], Pm[(size_t)il[l] * 160 + j], acc);
        SH1[(size_t)s * 192 + j] = f2bf(fmaxf(acc, 0.f));
    }
}

extern "C" void kernel_launch(void* const* d_in, const int* in_sizes, int n_in,
                              void* d_out, int out_size, void* d_ws, size_t ws_size,
                              hipStream_t stream) {
    const float* states = (const float*)d_in[0];
    const float* embeds = (const float*)d_in[1];
    const int* span_starts = (const int*)d_in[2];
    const int* span_lengths = (const int*)d_in[3];
    const float* Wa1 = (const float*)d_in[4];
    const float* ba1 = (const float*)d_in[5];
    const float* Wa2 = (const float*)d_in[6];
    const float* ba2 = (const float*)d_in[7];
    const float* Wa3 = (const float*)d_in[8];
    const float* ba3 = (const float*)d_in[9];
    const float* width_table = (const float*)d_in[10];
    const float* Ws1 = (const float*)d_in[11];
    const float* bs1 = (const float*)d_in[12];
    const float* Ws2 = (const float*)d_in[13];
    const float* bs2 = (const float*)d_in[14];
    const float* Ws3 = (const float*)d_in[15];
    const float* bs3 = (const float*)d_in[16];
    float* out = (float*)d_out;

    // ---- workspace layout ----
    char* w = (char*)d_ws;
    unsigned short* WtA  = (unsigned short*)w;  w += 480 * 1024 * 2;
    unsigned short* WtE  = (unsigned short*)w;  w += 160 * 512 * 2;
    unsigned short* Wa2t = (unsigned short*)w;  w += 160 * 192 * 2;
    unsigned short* Ws2t = (unsigned short*)w;  w += 160 * 192 * 2;
    float* PW    = (float*)w;                   w += 5632;
    float* attns = (float*)w;                   w += 8192 * 4;
    unsigned short* Sbf = (unsigned short*)w;   w += (size_t)T_TOK * A_DIM * 2;
    unsigned short* Ebf = (unsigned short*)w;   w += (size_t)T_TOK * E_DIM * 2;
    float* Ps = (float*)w;                      w += (size_t)T_TOK * 160 * 4;
    float* Pe = (float*)w;                      w += (size_t)T_TOK * 160 * 4;
    float* Pm = (float*)w;                      w += (size_t)T_TOK * 160 * 4;
    unsigned short* H1A = (unsigned short*)w;   w += (size_t)T_TOK * 192 * 2;   // bf16
    unsigned short* SH1 = (unsigned short*)w;   w += (size_t)S_SPAN * 192 * 2;  // bf16

    // zero H1A+SH1 (contiguous): clears pad cols; bf16 0x0000 == 0.0
    hipMemsetAsync(H1A, 0, ((size_t)T_TOK + S_SPAN) * 192 * 2, stream);

    // ---- input cast ----
    cast_kernel<<<(NS4 + NE4 + 255) / 256, 256, 0, stream>>>(states, embeds, Sbf, Ebf);

    // ---- weight prep (6 transposes + width proj in one launch) ----
    WTab wt;
    wt.g[0] = { Wa1,              WtA,              1024, 1024, (160*1024 + 255)/256 };
    wt.g[1] = { Ws1,              WtA + 160*1024,   1024, 1024, (160*1024 + 255)/256 };
    wt.g[2] = { Ws1 + 1024*150,   WtA + 320*1024,   1024, 1024, (160*1024 + 255)/256 };
    wt.g[3] = { Ws1 + 2048*150,   WtE,               512,  512, (160*512  + 255)/256 };
    wt.g[4] = { Wa2,              Wa2t,              150,  192, (160*192  + 255)/256 };
    wt.g[5] = { Ws2,              Ws2t,              150,  192, (160*192  + 255)/256 };
    wt.wt = width_table; wt.Ws1w = Ws1 + 2560*150; wt.PW = PW;
    int wblk = 0; for (int i = 0; i < 6; ++i) wblk += wt.g[i].nblk;
    wprep_kernel<<<wblk + 9, 256, 0, stream>>>(wt);

    // ---- fused GEMM1+2: 4 groups, one dispatch, 256 blocks ----
    GTab t1; t1.ng = 4;
    GG z = {};
    t1.g[0] = z; t1.g[0].A = Sbf; t1.g[0].lda = 1024; t1.g[0].W = WtA;            t1.g[0].K = 1024;
    t1.g[0].nrb = 64; t1.g[0].outh = H1A; t1.g[0].ldo = 192; t1.g[0].bias = ba1; t1.g[0].relu = 1;
    t1.g[1] = z; t1.g[1].A = Sbf; t1.g[1].lda = 1024; t1.g[1].W = WtA + 160*1024; t1.g[1].K = 1024;
    t1.g[1].nrb = 64; t1.g[1].outf = Ps;  t1.g[1].ldo = 160;
    t1.g[2] = z; t1.g[2].A = Sbf; t1.g[2].lda = 1024; t1.g[2].W = WtA + 320*1024; t1.g[2].K = 1024;
    t1.g[2].nrb = 64; t1.g[2].outf = Pe;  t1.g[2].ldo = 160;
    t1.g[3] = z; t1.g[3].A = Ebf; t1.g[3].lda = 512;  t1.g[3].W = WtE;            t1.g[3].K = 512;
    t1.g[3].nrb = 64; t1.g[3].outf = Pm;  t1.g[3].ldo = 160;
    gemm_fused<<<256, 256, 0, stream>>>(t1);

    // ---- attn layer2 + fused layer3 dot -> attns ----
    GTab t2; t2.ng = 1;
    t2.g[0] = z; t2.g[0].A = H1A; t2.g[0].lda = 192; t2.g[0].W = Wa2t; t2.g[0].K = 192;
    t2.g[0].nrb = 64; t2.g[0].bias = ba2; t2.g[0].dotv = Wa3; t2.g[0].dotb = ba3; t2.g[0].dotout = attns;
    gemm_fused<<<64, 256, 0, stream>>>(t2);

    // ---- span layer1 -> SH1 (bf16) ----
    span_l1_kernel<<<S_SPAN / 4, 256, 0, stream>>>(attns, span_starts, span_lengths,
                                                   Ps, Pe, Pm, PW, bs1, SH1);

    // ---- span layer2 + fused layer3 dot -> out ----
    GTab t3; t3.ng = 1;
    t3.g[0] = z; t3.g[0].A = SH1; t3.g[0].lda = 192; t3.g[0].W = Ws2t; t3.g[0].K = 192;
    t3.g[0].nrb = 256; t3.g[0].bias = bs2; t3.g[0].dotv = Ws3; t3.g[0].dotb = bs3; t3.g[0].dotout = out;
    gemm_fused<<<256, 256, 0, stream>>>(t3);
}

// Round 5
// 180.841 us; speedup vs baseline: 5.8720x; 1.2330x over previous
//
#include <hip/hip_runtime.h>
#include <math.h>

#define T_TOK 8192
#define A_DIM 1024
#define E_DIM 512
#define S_SPAN 32768
#define HID 150

typedef __attribute__((ext_vector_type(8))) short short8;
typedef __attribute__((ext_vector_type(4))) float f32x4;
typedef __attribute__((ext_vector_type(4))) unsigned int u32x4;
typedef __attribute__((ext_vector_type(4))) unsigned short u16x4;

__device__ __forceinline__ unsigned short f2bf(float f) {
    unsigned int u = __builtin_bit_cast(unsigned int, f);
    u += 0x7FFFu + ((u >> 16) & 1u);          // RNE
    return (unsigned short)(u >> 16);
}

// ---------------------------------------------------------------------------
// fused prep: input cast (fp32->bf16) + 6 weight transposes + width proj
// ---------------------------------------------------------------------------
#define NS4 (T_TOK * A_DIM / 4)   // 2097152
#define NE4 (T_TOK * E_DIM / 4)   // 1048576
#define NCAST ((NS4 + NE4 + 255) / 256)

struct WConv { const float* src; unsigned short* dst; int K0; int Kpad; int nblk; };
struct PrepTab {
    const float* s; const float* e; unsigned short* sd; unsigned short* ed;
    WConv g[6];
    const float* wt; const float* Ws1w; float* PW;
};

__global__ __launch_bounds__(256) void prep_kernel(PrepTab tab) {
    int b = blockIdx.x;
    if (b < NCAST) {
        int idx = b * 256 + threadIdx.x;
        const float* src; unsigned short* dst;
        if (idx < NS4) { src = tab.s; dst = tab.sd; }
        else { idx -= NS4; if (idx >= NE4) return; src = tab.e; dst = tab.ed; }
        f32x4 v = *(const f32x4*)(src + (size_t)idx * 4);
        u16x4 o;
        o.x = f2bf(v.x); o.y = f2bf(v.y); o.z = f2bf(v.z); o.w = f2bf(v.w);
        *(u16x4*)(dst + (size_t)idx * 4) = o;
        return;
    }
    b -= NCAST;
    #pragma unroll
    for (int gi = 0; gi < 6; ++gi) {
        if (b < tab.g[gi].nblk) {
            int idx = b * 256 + threadIdx.x;               // idx = k*160 + j
            int Kpad = tab.g[gi].Kpad;
            if (idx < Kpad * 160) {
                int k = idx / 160, j = idx - k * 160;
                float v = (j < HID && k < tab.g[gi].K0)
                          ? tab.g[gi].src[(size_t)k * HID + j] : 0.f;   // coalesced read
                tab.g[gi].dst[(size_t)j * Kpad + k] = f2bf(v);          // scattered write
            }
            return;
        }
        b -= tab.g[gi].nblk;
    }
    // width projection: 9 blocks
    int j = threadIdx.x;
    if (j < HID) {
        float acc = 0.f;
        for (int k = 0; k < 20; ++k)
            acc = fmaf(tab.wt[b * 20 + k], tab.Ws1w[k * HID + j], acc);
        tab.PW[b * HID + j] = acc;
    }
}

// ---------------------------------------------------------------------------
// unified MFMA GEMM, double-buffered + software-pipelined.
// per group: C[M x 160] = A(bf16,[M x K]) @ W(bf16,[160 x K] k-contig)
// block = 4 waves x 16 rows = 64 rows, 10 n-tiles, BK=64, 2 LDS buffers.
// epilogue: fp32 / bf16 store (+bias+relu) or fused final dot.
// ---------------------------------------------------------------------------
struct GG {
    const unsigned short* A; int lda;
    const unsigned short* W; int K; int nrb;
    float* outf; unsigned short* outh; int ldo;
    const float* bias; int relu;
    const float* dotv; const float* dotb; float* dotout;
};
struct GTab { GG g[4]; int ng; };

__global__ __launch_bounds__(256) void gemm_fused(GTab tab) {
    constexpr int LDW = 88;   // ushort stride; 176 B rows -> only 2-way bank alias (free)
    __shared__ unsigned short WtL[2][160 * LDW];

    int b = blockIdx.x;
    int gi = 0;
    while (gi < tab.ng - 1 && b >= tab.g[gi].nrb) { b -= tab.g[gi].nrb; ++gi; }
    const GG G = tab.g[gi];

    const int tid = threadIdx.x;
    const int wid = tid >> 6;
    const int lane = tid & 63;
    const int l15 = lane & 15;
    const int quad = lane >> 4;
    const int row0 = b * 64 + wid * 16 + l15;
    const int K = G.K;
    const int nch = K >> 6;
    const unsigned short* Arow = G.A + (size_t)row0 * G.lda;

    // staging registers for W chunk: 1280 16B units / 256 thr = 5 each
    u32x4 stg[5];
    int sn[5], sk[5];
    #pragma unroll
    for (int i = 0; i < 5; ++i) { int u = tid + i * 256; sn[i] = u >> 3; sk[i] = (u & 7) * 8; }

    f32x4 acc[10];
    #pragma unroll
    for (int nt = 0; nt < 10; ++nt) acc[nt] = (f32x4){0.f, 0.f, 0.f, 0.f};

    // prologue: load chunk 0 W -> LDS buf0, A frags chunk 0 -> regs
    #pragma unroll
    for (int i = 0; i < 5; ++i)
        stg[i] = *(const u32x4*)(G.W + (size_t)sn[i] * K + sk[i]);
    short8 avc0 = *(const short8*)(Arow + quad * 8);
    short8 avc1 = *(const short8*)(Arow + 32 + quad * 8);
    #pragma unroll
    for (int i = 0; i < 5; ++i)
        *(u32x4*)&WtL[0][sn[i] * LDW + sk[i]] = stg[i];
    __syncthreads();

    for (int c = 0; c < nch; ++c) {
        const int pb = c & 1;
        short8 avn0, avn1;
        const bool more = (c + 1 < nch);
        if (more) {
            const int kn = (c + 1) << 6;
            #pragma unroll
            for (int i = 0; i < 5; ++i)
                stg[i] = *(const u32x4*)(G.W + (size_t)sn[i] * K + kn + sk[i]);
            avn0 = *(const short8*)(Arow + kn + quad * 8);
            avn1 = *(const short8*)(Arow + kn + 32 + quad * 8);
        }
        // compute chunk c (loads for c+1 in flight)
        #pragma unroll
        for (int nt = 0; nt < 10; ++nt) {
            short8 bv0 = *(const short8*)&WtL[pb][(nt * 16 + l15) * LDW + quad * 8];
            acc[nt] = __builtin_amdgcn_mfma_f32_16x16x32_bf16(avc0, bv0, acc[nt], 0, 0, 0);
            short8 bv1 = *(const short8*)&WtL[pb][(nt * 16 + l15) * LDW + 32 + quad * 8];
            acc[nt] = __builtin_amdgcn_mfma_f32_16x16x32_bf16(avc1, bv1, acc[nt], 0, 0, 0);
        }
        if (more) {
            #pragma unroll
            for (int i = 0; i < 5; ++i)
                *(u32x4*)&WtL[pb ^ 1][sn[i] * LDW + sk[i]] = stg[i];
            avc0 = avn0; avc1 = avn1;
        }
        __syncthreads();
    }

    const int rbase = b * 64 + wid * 16 + quad * 4;
    if (G.dotout) {
        float part[4] = {0.f, 0.f, 0.f, 0.f};
        #pragma unroll
        for (int nt = 0; nt < 10; ++nt) {
            int col = nt * 16 + l15;
            float bv_ = (col < HID) ? G.bias[col] : 0.f;
            float vv = (col < HID) ? G.dotv[col] : 0.f;
            #pragma unroll
            for (int r = 0; r < 4; ++r)
                part[r] += fmaxf(acc[nt][r] + bv_, 0.f) * vv;
        }
        #pragma unroll
        for (int r = 0; r < 4; ++r) {
            float p = part[r];
            #pragma unroll
            for (int off = 1; off < 16; off <<= 1) p += __shfl_xor(p, off);
            if (l15 == 0) G.dotout[rbase + r] = p + G.dotb[0];
        }
    } else {
        #pragma unroll
        for (int nt = 0; nt < 10; ++nt) {
            int col = nt * 16 + l15;
            float bv_ = (G.bias != nullptr && col < HID) ? G.bias[col] : 0.f;
            #pragma unroll
            for (int r = 0; r < 4; ++r) {
                int row = rbase + r;
                float v = acc[nt][r] + bv_;
                if (G.relu) v = fmaxf(v, 0.f);
                if (G.outh) G.outh[(size_t)row * G.ldo + col] = f2bf(v);
                else        G.outf[(size_t)row * G.ldo + col] = v;
            }
        }
    }
}

// ---------------------------------------------------------------------------
// span layer-1: one wave per span; writes SH1 bf16 [S x 192] cols 0..149.
// ---------------------------------------------------------------------------
__global__ __launch_bounds__(256) void span_l1_kernel(const float* __restrict__ attns,
                                                      const int* __restrict__ starts,
                                                      const int* __restrict__ lens,
                                                      const float* __restrict__ Ps,
                                                      const float* __restrict__ Pe,
                                                      const float* __restrict__ Pm,
                                                      const float* __restrict__ PW,
                                                      const float* __restrict__ bs1,
                                                      unsigned short* __restrict__ SH1) {
    const int wid = threadIdx.x >> 6, lane = threadIdx.x & 63;
    const int s = blockIdx.x * 4 + wid;
    const int start = starts[s];
    const int len = lens[s];

    const int iv = min(start + lane, T_TOK - 1);
    float a = (lane <= len) ? attns[iv] : -INFINITY;
    float m = a;
    #pragma unroll
    for (int off = 32; off; off >>= 1) m = fmaxf(m, __shfl_xor(m, off));
    float e = (lane <= len) ? __expf(a - m) : 0.f;
    float ssum = e;
    #pragma unroll
    for (int off = 32; off; off >>= 1) ssum += __shfl_xor(ssum, off);
    float wv = e / ssum;

    float wl[10]; int il[10];
    #pragma unroll
    for (int l = 0; l < 10; ++l) { wl[l] = __shfl(wv, l); il[l] = __shfl(iv, l); }

    const int end = start + len;
    const int width = len + 1;
    const int bucket = (width >= 1) + (width >= 2) + (width >= 3) + (width >= 4) +
                       (width >= 8) + (width >= 16) + (width >= 32) + (width >= 64);

    for (int j = lane; j < HID; j += 64) {
        float acc = bs1[j] + Ps[(size_t)start * 160 + j] + Pe[(size_t)end * 160 + j] +
                    PW[bucket * HID + j];
        #pragma unroll
        for (int l = 0; l < 10; ++l) acc = fmaf(wl[l], Pm[(size_t)il[l] * 160 + j], acc);
        SH1[(size_t)s * 192 + j] = f2bf(fmaxf(acc, 0.f));
    }
}

extern "C" void kernel_launch(void* const* d_in, const int* in_sizes, int n_in,
                              void* d_out, int out_size, void* d_ws, size_t ws_size,
                              hipStream_t stream) {
    const float* states = (const float*)d_in[0];
    const float* embeds = (const float*)d_in[1];
    const int* span_starts = (const int*)d_in[2];
    const int* span_lengths = (const int*)d_in[3];
    const float* Wa1 = (const float*)d_in[4];
    const float* ba1 = (const float*)d_in[5];
    const float* Wa2 = (const float*)d_in[6];
    const float* ba2 = (const float*)d_in[7];
    const float* Wa3 = (const float*)d_in[8];
    const float* ba3 = (const float*)d_in[9];
    const float* width_table = (const float*)d_in[10];
    const float* Ws1 = (const float*)d_in[11];
    const float* bs1 = (const float*)d_in[12];
    const float* Ws2 = (const float*)d_in[13];
    const float* bs2 = (const float*)d_in[14];
    const float* Ws3 = (const float*)d_in[15];
    const float* bs3 = (const float*)d_in[16];
    float* out = (float*)d_out;

    // ---- workspace layout ----
    char* w = (char*)d_ws;
    unsigned short* WtA  = (unsigned short*)w;  w += 480 * 1024 * 2;
    unsigned short* WtE  = (unsigned short*)w;  w += 160 * 512 * 2;
    unsigned short* Wa2t = (unsigned short*)w;  w += 160 * 192 * 2;
    unsigned short* Ws2t = (unsigned short*)w;  w += 160 * 192 * 2;
    float* PW    = (float*)w;                   w += 5632;
    float* attns = (float*)w;                   w += 8192 * 4;
    unsigned short* Sbf = (unsigned short*)w;   w += (size_t)T_TOK * A_DIM * 2;
    unsigned short* Ebf = (unsigned short*)w;   w += (size_t)T_TOK * E_DIM * 2;
    float* Ps = (float*)w;                      w += (size_t)T_TOK * 160 * 4;
    float* Pe = (float*)w;                      w += (size_t)T_TOK * 160 * 4;
    float* Pm = (float*)w;                      w += (size_t)T_TOK * 160 * 4;
    unsigned short* H1A = (unsigned short*)w;   w += (size_t)T_TOK * 192 * 2;   // bf16
    unsigned short* SH1 = (unsigned short*)w;   w += (size_t)S_SPAN * 192 * 2;  // bf16
    // NOTE: no memset needed — pad cols of H1A/SH1 multiply zeroed W rows;
    // 0xAA poison is finite, 0 * finite = 0.

    // ---- fused prep: cast + weight transposes + width proj ----
    PrepTab pt;
    pt.s = states; pt.e = embeds; pt.sd = Sbf; pt.ed = Ebf;
    pt.g[0] = { Wa1,              WtA,              1024, 1024, (160*1024 + 255)/256 };
    pt.g[1] = { Ws1,              WtA + 160*1024,   1024, 1024, (160*1024 + 255)/256 };
    pt.g[2] = { Ws1 + 1024*150,   WtA + 320*1024,   1024, 1024, (160*1024 + 255)/256 };
    pt.g[3] = { Ws1 + 2048*150,   WtE,               512,  512, (160*512  + 255)/256 };
    pt.g[4] = { Wa2,              Wa2t,              150,  192, (160*192  + 255)/256 };
    pt.g[5] = { Ws2,              Ws2t,              150,  192, (160*192  + 255)/256 };
    pt.wt = width_table; pt.Ws1w = Ws1 + 2560*150; pt.PW = PW;
    int wblk = 0; for (int i = 0; i < 6; ++i) wblk += pt.g[i].nblk;
    prep_kernel<<<NCAST + wblk + 9, 256, 0, stream>>>(pt);

    GG z = {};

    // ---- fused GEMM1+2: 4 groups, 512 blocks (2 blocks/CU) ----
    GTab t1; t1.ng = 4;
    t1.g[0] = z; t1.g[0].A = Sbf; t1.g[0].lda = 1024; t1.g[0].W = WtA;            t1.g[0].K = 1024;
    t1.g[0].nrb = 128; t1.g[0].outh = H1A; t1.g[0].ldo = 192; t1.g[0].bias = ba1; t1.g[0].relu = 1;
    t1.g[1] = z; t1.g[1].A = Sbf; t1.g[1].lda = 1024; t1.g[1].W = WtA + 160*1024; t1.g[1].K = 1024;
    t1.g[1].nrb = 128; t1.g[1].outf = Ps;  t1.g[1].ldo = 160;
    t1.g[2] = z; t1.g[2].A = Sbf; t1.g[2].lda = 1024; t1.g[2].W = WtA + 320*1024; t1.g[2].K = 1024;
    t1.g[2].nrb = 128; t1.g[2].outf = Pe;  t1.g[2].ldo = 160;
    t1.g[3] = z; t1.g[3].A = Ebf; t1.g[3].lda = 512;  t1.g[3].W = WtE;            t1.g[3].K = 512;
    t1.g[3].nrb = 128; t1.g[3].outf = Pm;  t1.g[3].ldo = 160;
    gemm_fused<<<512, 256, 0, stream>>>(t1);

    // ---- attn layer2 + fused layer3 dot -> attns ----
    GTab t2; t2.ng = 1;
    t2.g[0] = z; t2.g[0].A = H1A; t2.g[0].lda = 192; t2.g[0].W = Wa2t; t2.g[0].K = 192;
    t2.g[0].nrb = 128; t2.g[0].bias = ba2; t2.g[0].dotv = Wa3; t2.g[0].dotb = ba3; t2.g[0].dotout = attns;
    gemm_fused<<<128, 256, 0, stream>>>(t2);

    // ---- span layer1 -> SH1 (bf16) ----
    span_l1_kernel<<<S_SPAN / 4, 256, 0, stream>>>(attns, span_starts, span_lengths,
                                                   Ps, Pe, Pm, PW, bs1, SH1);

    // ---- span layer2 + fused layer3 dot -> out ----
    GTab t3; t3.ng = 1;
    t3.g[0] = z; t3.g[0].A = SH1; t3.g[0].lda = 192; t3.g[0].W = Ws2t; t3.g[0].K = 192;
    t3.g[0].nrb = 512; t3.g[0].bias = bs2; t3.g[0].dotv = Ws3; t3.g[0].dotb = bs3; t3.g[0].dotout = out;
    gemm_fused<<<512, 256, 0, stream>>>(t3);
}